// Round 1
// baseline (328.627 us; speedup 1.0000x reference)
//
#include <hip/hip_runtime.h>
#include <hip/hip_bf16.h>

// Problem constants (B,S,D,H fixed by setup_inputs)
#define B_  8
#define S_  1024
#define D_  768
#define H_  12
#define DH_ 64

typedef __attribute__((ext_vector_type(8))) short bf16x8;
typedef __attribute__((ext_vector_type(4))) float f32x4;

__device__ inline short f2bf(float f) {
    unsigned u = __builtin_bit_cast(unsigned, f);
    u = (u + 0x7fffu + ((u >> 16) & 1u)) >> 16;   // RNE
    return (short)u;
}

// ---------------------------------------------------------------------------
// Kernel 1: Y = relu(X @ W^T) for X in {q,k,v} stacked along M (24576 rows).
// Outputs bf16: q1,k1 as [B][H][S][Dh]; v as transposed [B][H][Dh][S] so the
// PV matmul's B-operand reads are contiguous.
// Tile: BM=64, BN=64, BK=32; 4 waves, each computes 16 rows x 64 cols.
// ---------------------------------------------------------------------------
__global__ __launch_bounds__(256) void proj_kernel(
    const float* __restrict__ q, const float* __restrict__ k,
    const float* __restrict__ v, const float* __restrict__ W,
    short* __restrict__ q1, short* __restrict__ k1, short* __restrict__ v1t)
{
    __shared__ short As[64][40];   // pad 32->40: b128 reads spread across bank groups
    __shared__ short Bs[64][40];

    int blk = blockIdx.x;
    int nt  = blk % 12;            // N-tile (768/64) fastest -> adjacent blocks share A via L2
    int mt  = blk / 12;
    int t   = mt >> 7;             // 128 m-tiles per input: 0=q,1=k,2=v
    int m0  = (mt & 127) * 64;
    const float* X = (t == 0) ? q : (t == 1) ? k : v;

    int tid  = threadIdx.x;
    int lane = tid & 63;
    int w    = tid >> 6;
    int srow = tid >> 2;           // staging: 64 rows x (4 thr x 8 floats)
    int scol = (tid & 3) * 8;
    int n0   = nt * 64;
    int l15  = lane & 15;
    int mr   = (w << 4) + l15;     // A-fragment row within tile
    int k0   = (lane >> 4) << 3;   // A/B fragment k-offset

    f32x4 acc[4];
    #pragma unroll
    for (int n = 0; n < 4; n++) acc[n] = (f32x4){0.f, 0.f, 0.f, 0.f};

    const float* ap = X + (size_t)(m0 + srow) * D_ + scol;
    const float* bp = W + (size_t)(n0 + srow) * D_ + scol;

    for (int kb = 0; kb < D_; kb += 32) {
        __syncthreads();
        f32x4 a0 = *(const f32x4*)(ap + kb);
        f32x4 a1 = *(const f32x4*)(ap + kb + 4);
        f32x4 b0 = *(const f32x4*)(bp + kb);
        f32x4 b1 = *(const f32x4*)(bp + kb + 4);
        bf16x8 av, bv;
        #pragma unroll
        for (int i = 0; i < 4; i++) {
            av[i] = f2bf(a0[i]); av[i + 4] = f2bf(a1[i]);
            bv[i] = f2bf(b0[i]); bv[i + 4] = f2bf(b1[i]);
        }
        *(bf16x8*)&As[srow][scol] = av;
        *(bf16x8*)&Bs[srow][scol] = bv;
        __syncthreads();

        bf16x8 af = *(const bf16x8*)&As[mr][k0];
        #pragma unroll
        for (int n = 0; n < 4; n++) {
            bf16x8 bf = *(const bf16x8*)&Bs[(n << 4) + l15][k0];
            acc[n] = __builtin_amdgcn_mfma_f32_16x16x32_bf16(af, bf, acc[n], 0, 0, 0);
        }
    }

    // Epilogue: relu -> bf16 -> scatter to head-major layouts.
    #pragma unroll
    for (int n = 0; n < 4; n++) {
        int col = n0 + (n << 4) + l15;
        int h = col >> 6, dh = col & 63;
        #pragma unroll
        for (int r = 0; r < 4; r++) {
            int m  = m0 + (w << 4) + ((lane >> 4) << 2) + r;
            int bb = m >> 10, ss = m & 1023;
            short val = f2bf(fmaxf(acc[n][r], 0.f));
            if (t == 2)
                v1t[(((size_t)bb * H_ + h) * DH_ + dh) * S_ + ss] = val;
            else {
                short* dst = t ? k1 : q1;
                dst[(((size_t)bb * H_ + h) * S_ + ss) * DH_ + dh] = val;
            }
        }
    }
}

// ---------------------------------------------------------------------------
// Kernel 2: flash attention. Block = (b,h, q-tile of 64 rows); 4 waves, each
// owns 16 q-rows. Q in registers; K/V direct from global (L2-resident tiles).
// Online softmax on the C/D fragment layout; P transposed via per-wave LDS.
// Writes raw attention output (pre-residual) to out[B][S][D].
// ---------------------------------------------------------------------------
__global__ __launch_bounds__(256) void attn_kernel(
    const short* __restrict__ q1, const short* __restrict__ k1,
    const short* __restrict__ v1t, float* __restrict__ out)
{
    __shared__ short P[4][16][72];   // per-wave P transpose buffer (pad 64->72)

    int blk = blockIdx.x;
    int qt  = blk & 15;
    int bh  = blk >> 4;
    int bb  = bh / H_, hh = bh % H_;
    int tid = threadIdx.x, lane = tid & 63, w = tid >> 6;
    int l15 = lane & 15;
    int k0  = (lane >> 4) << 3;

    const short* Qp = q1  + (size_t)bh * S_ * DH_;
    const short* Kp = k1  + (size_t)bh * S_ * DH_;
    const short* Vp = v1t + (size_t)bh * DH_ * S_;

    int qr_a = qt * 64 + (w << 4) + l15;             // A-fragment q-row
    bf16x8 qa0 = *(const bf16x8*)(Qp + qr_a * DH_ + k0);
    bf16x8 qa1 = *(const bf16x8*)(Qp + qr_a * DH_ + 32 + k0);

    float m[4], lsum[4];
    f32x4 acc[4];
    #pragma unroll
    for (int r = 0; r < 4; r++) { m[r] = -1e30f; lsum[r] = 0.f; }
    #pragma unroll
    for (int n = 0; n < 4; n++) acc[n] = (f32x4){0.f, 0.f, 0.f, 0.f};

    for (int kv = 0; kv < S_; kv += 64) {
        f32x4 s[4];
        #pragma unroll
        for (int n = 0; n < 4; n++) s[n] = (f32x4){0.f, 0.f, 0.f, 0.f};

        #pragma unroll
        for (int j = 0; j < 2; j++) {
            bf16x8 aq = j ? qa1 : qa0;
            #pragma unroll
            for (int n = 0; n < 4; n++) {
                bf16x8 bk = *(const bf16x8*)(Kp + (kv + (n << 4) + l15) * DH_ + j * 32 + k0);
                s[n] = __builtin_amdgcn_mfma_f32_16x16x32_bf16(aq, bk, s[n], 0, 0, 0);
            }
        }
        #pragma unroll
        for (int n = 0; n < 4; n++) s[n] *= 0.125f;   // 1/sqrt(64)

        // online softmax: lane holds rows (lane>>4)*4+r, col = l15 + 16n
        #pragma unroll
        for (int r = 0; r < 4; r++) {
            float mt = fmaxf(fmaxf(s[0][r], s[1][r]), fmaxf(s[2][r], s[3][r]));
            mt = fmaxf(mt, __shfl_xor(mt, 1));
            mt = fmaxf(mt, __shfl_xor(mt, 2));
            mt = fmaxf(mt, __shfl_xor(mt, 4));
            mt = fmaxf(mt, __shfl_xor(mt, 8));
            float mn = fmaxf(m[r], mt);
            float sc = __expf(m[r] - mn);
            float rs = 0.f;
            #pragma unroll
            for (int n = 0; n < 4; n++) {
                float p = __expf(s[n][r] - mn);
                s[n][r] = p;
                rs += p;
            }
            rs += __shfl_xor(rs, 1);
            rs += __shfl_xor(rs, 2);
            rs += __shfl_xor(rs, 4);
            rs += __shfl_xor(rs, 8);
            lsum[r] = lsum[r] * sc + rs;
            m[r] = mn;
            #pragma unroll
            for (int n = 0; n < 4; n++) acc[n][r] *= sc;
        }

        // transpose P (C/D layout -> A-fragment layout) through per-wave LDS
        #pragma unroll
        for (int n = 0; n < 4; n++)
            #pragma unroll
            for (int r = 0; r < 4; r++)
                P[w][((lane >> 4) << 2) + r][(n << 4) + l15] = f2bf(s[n][r]);
        // same-wave write->read: compiler inserts lgkmcnt wait (same LDS object)

        #pragma unroll
        for (int j = 0; j < 2; j++) {
            bf16x8 pa = *(const bf16x8*)&P[w][l15][j * 32 + k0];
            #pragma unroll
            for (int n = 0; n < 4; n++) {
                bf16x8 bv = *(const bf16x8*)(Vp + ((n << 4) + l15) * S_ + kv + j * 32 + k0);
                acc[n] = __builtin_amdgcn_mfma_f32_16x16x32_bf16(pa, bv, acc[n], 0, 0, 0);
            }
        }
    }

    #pragma unroll
    for (int n = 0; n < 4; n++) {
        int dh = (n << 4) + l15;
        #pragma unroll
        for (int r = 0; r < 4; r++) {
            int qr = qt * 64 + (w << 4) + ((lane >> 4) << 2) + r;
            out[((size_t)bb * S_ + qr) * D_ + hh * DH_ + dh] = acc[n][r] / lsum[r];
        }
    }
}

// ---------------------------------------------------------------------------
// Kernel 3: in-place y = LN(2*out + q) * gamma + beta, one block per row.
// ---------------------------------------------------------------------------
__global__ __launch_bounds__(256) void ln_kernel(
    const float* __restrict__ qin, const float* __restrict__ gamma,
    const float* __restrict__ beta, float* __restrict__ out)
{
    int row = blockIdx.x;
    int tid = threadIdx.x;
    size_t base = (size_t)row * D_;

    float vbuf[3];
    float sum = 0.f, sq = 0.f;
    #pragma unroll
    for (int i = 0; i < 3; i++) {
        int idx = tid + i * 256;
        float x = 2.f * out[base + idx] + qin[base + idx];
        vbuf[i] = x;
        sum += x;
        sq  += x * x;
    }
    #pragma unroll
    for (int msk = 1; msk < 64; msk <<= 1) {
        sum += __shfl_xor(sum, msk);
        sq  += __shfl_xor(sq, msk);
    }
    __shared__ float s1[4], s2[4];
    if ((tid & 63) == 0) { s1[tid >> 6] = sum; s2[tid >> 6] = sq; }
    __syncthreads();
    sum = s1[0] + s1[1] + s1[2] + s1[3];
    sq  = s2[0] + s2[1] + s2[2] + s2[3];
    float mu   = sum * (1.f / D_);
    float var  = sq * (1.f / D_) - mu * mu;
    float rstd = rsqrtf(var + 1e-5f);
    #pragma unroll
    for (int i = 0; i < 3; i++) {
        int idx = tid + i * 256;
        out[base + idx] = (vbuf[i] - mu) * rstd * gamma[idx] + beta[idx];
    }
}

// ---------------------------------------------------------------------------
extern "C" void kernel_launch(void* const* d_in, const int* in_sizes, int n_in,
                              void* d_out, int out_size, void* d_ws, size_t ws_size,
                              hipStream_t stream)
{
    const float* q     = (const float*)d_in[0];
    const float* k     = (const float*)d_in[1];
    const float* v     = (const float*)d_in[2];
    const float* W     = (const float*)d_in[3];
    const float* gamma = (const float*)d_in[4];
    const float* beta  = (const float*)d_in[5];

    size_t per = (size_t)B_ * H_ * S_ * DH_;   // 6291456 bf16 elements each
    short* q1  = (short*)d_ws;
    short* k1  = q1 + per;
    short* v1t = k1 + per;
    float* out = (float*)d_out;

    // 3*8192/64 m-tiles * 12 n-tiles
    proj_kernel<<<dim3(384 * 12), dim3(256), 0, stream>>>(q, k, v, W, q1, k1, v1t);
    // B*H * (1024/64) q-tiles
    attn_kernel<<<dim3(B_ * H_ * 16), dim3(256), 0, stream>>>(q1, k1, v1t, out);
    // one block per (b,s) row
    ln_kernel<<<dim3(B_ * S_), dim3(256), 0, stream>>>(q, gamma, beta, out);
}

// Round 2
// 221.462 us; speedup vs baseline: 1.4839x; 1.4839x over previous
//
#include <hip/hip_runtime.h>
#include <hip/hip_bf16.h>

// Problem constants (B,S,D,H fixed by setup_inputs)
#define B_  8
#define S_  1024
#define D_  768
#define H_  12
#define DH_ 64

typedef __attribute__((ext_vector_type(8))) short bf16x8;
typedef __attribute__((ext_vector_type(4))) float f32x4;
typedef __attribute__((ext_vector_type(16))) float f32x16;

__device__ inline short f2bf(float f) {
    unsigned u = __builtin_bit_cast(unsigned, f);
    u = (u + 0x7fffu + ((u >> 16) & 1u)) >> 16;   // RNE
    return (short)u;
}
__device__ inline float exp2_fast(float x) {
    float r; asm("v_exp_f32 %0, %1" : "=v"(r) : "v"(x)); return r;
}
__device__ inline unsigned cvt_pk_bf16(float lo, float hi) {
    unsigned r; asm("v_cvt_pk_bf16_f32 %0, %1, %2" : "=v"(r) : "v"(lo), "v"(hi)); return r;
}
__device__ inline float rcp_fast(float x) {
    float r; asm("v_rcp_f32 %0, %1" : "=v"(r) : "v"(x)); return r;
}

// ---------------------------------------------------------------------------
// Kernel 1: Y = relu(X @ W^T) for X in {q,k,v} stacked along M (24576 rows).
// Outputs bf16: q1,k1 as [B][H][S][Dh]; v as transposed [B][H][Dh][S].
// k1 is pre-scaled by 1/sqrt(Dh)*log2(e) so attention works in exp2 domain.
// ---------------------------------------------------------------------------
__global__ __launch_bounds__(256) void proj_kernel(
    const float* __restrict__ q, const float* __restrict__ k,
    const float* __restrict__ v, const float* __restrict__ W,
    short* __restrict__ q1, short* __restrict__ k1, short* __restrict__ v1t)
{
    __shared__ short As[64][40];
    __shared__ short Bs[64][40];

    int blk = blockIdx.x;
    int nt  = blk % 12;
    int mt  = blk / 12;
    int t   = mt >> 7;             // 0=q,1=k,2=v
    int m0  = (mt & 127) * 64;
    const float* X = (t == 0) ? q : (t == 1) ? k : v;

    int tid  = threadIdx.x;
    int lane = tid & 63;
    int w    = tid >> 6;
    int srow = tid >> 2;
    int scol = (tid & 3) * 8;
    int n0   = nt * 64;
    int l15  = lane & 15;
    int mr   = (w << 4) + l15;
    int k0   = (lane >> 4) << 3;

    f32x4 acc[4];
    #pragma unroll
    for (int n = 0; n < 4; n++) acc[n] = (f32x4){0.f, 0.f, 0.f, 0.f};

    const float* ap = X + (size_t)(m0 + srow) * D_ + scol;
    const float* bp = W + (size_t)(n0 + srow) * D_ + scol;

    for (int kb = 0; kb < D_; kb += 32) {
        __syncthreads();
        f32x4 a0 = *(const f32x4*)(ap + kb);
        f32x4 a1 = *(const f32x4*)(ap + kb + 4);
        f32x4 b0 = *(const f32x4*)(bp + kb);
        f32x4 b1 = *(const f32x4*)(bp + kb + 4);
        bf16x8 av, bv;
        #pragma unroll
        for (int i = 0; i < 4; i++) {
            av[i] = f2bf(a0[i]); av[i + 4] = f2bf(a1[i]);
            bv[i] = f2bf(b0[i]); bv[i + 4] = f2bf(b1[i]);
        }
        *(bf16x8*)&As[srow][scol] = av;
        *(bf16x8*)&Bs[srow][scol] = bv;
        __syncthreads();

        bf16x8 af = *(const bf16x8*)&As[mr][k0];
        #pragma unroll
        for (int n = 0; n < 4; n++) {
            bf16x8 bf = *(const bf16x8*)&Bs[(n << 4) + l15][k0];
            acc[n] = __builtin_amdgcn_mfma_f32_16x16x32_bf16(af, bf, acc[n], 0, 0, 0);
        }
    }

    #pragma unroll
    for (int n = 0; n < 4; n++) {
        int col = n0 + (n << 4) + l15;
        int h = col >> 6, dh = col & 63;
        #pragma unroll
        for (int r = 0; r < 4; r++) {
            int m  = m0 + (w << 4) + ((lane >> 4) << 2) + r;
            int bb = m >> 10, ss = m & 1023;
            float av = fmaxf(acc[n][r], 0.f);
            if (t == 1) av *= 0.18033688011112793f;   // 1/sqrt(64)*log2(e)
            short val = f2bf(av);
            if (t == 2)
                v1t[(((size_t)bb * H_ + h) * DH_ + dh) * S_ + ss] = val;
            else {
                short* dst = t ? k1 : q1;
                dst[(((size_t)bb * H_ + h) * S_ + ss) * DH_ + dh] = val;
            }
        }
    }
}

// ---------------------------------------------------------------------------
// Kernel 2: flash attention, swapped-QK^T 32x32x16 structure (m214-style).
// Each wave owns 32 q-rows. s = mfma(K, Q) puts each q-row's 32 KV scores
// in-lane (16) + lane^32 (16): softmax is an in-register tree + one shfl.
// P is packed to bf16 A-fragments via v_cvt_pk_bf16_f32 + shfl_xor(32).
// No LDS in the main loop; K/V read direct from global (L2-resident).
// ---------------------------------------------------------------------------
__global__ __launch_bounds__(256) void attn_kernel(
    const short* __restrict__ q1, const short* __restrict__ k1,
    const short* __restrict__ v1t, float* __restrict__ out)
{
    __shared__ float lsum_lds[4][32];

    // XCD swizzle: blocks of the same head land on the same XCD (%8 mapping)
    int d    = blockIdx.x;                       // 0..767
    int head = (d & 7) + ((d >> 6) << 3);        // 0..95
    int qi   = (d >> 3) & 7;                     // q-block octet within head
    int bb   = head / H_, hh = head % H_;

    int tid = threadIdx.x, lane = tid & 63, w = tid >> 6;
    int l31 = lane & 31, hi = lane >> 5;
    int qbase = (qi * 4 + w) * 32;

    const short* Qp = q1  + (size_t)head * S_ * DH_;
    const short* Kp = k1  + (size_t)head * S_ * DH_;
    const short* Vp = v1t + (size_t)head * DH_ * S_;

    // Q B-fragments, resident for the whole kernel
    bf16x8 qf[4];
    #pragma unroll
    for (int kb = 0; kb < 4; kb++)
        qf[kb] = *(const bf16x8*)(Qp + (size_t)(qbase + l31) * DH_ + kb * 16 + hi * 8);

    f32x16 o0, o1;
    #pragma unroll
    for (int r = 0; r < 16; r++) { o0[r] = 0.f; o1[r] = 0.f; }
    float mreg = -1e30f, lsum = 0.f;

    for (int kv0 = 0; kv0 < S_; kv0 += 32) {
        // K A-fragments (k1 pre-scaled, so s is already in log2 domain)
        const short* kp = Kp + (size_t)(kv0 + l31) * DH_ + hi * 8;
        bf16x8 kf0 = *(const bf16x8*)(kp);
        bf16x8 kf1 = *(const bf16x8*)(kp + 16);
        bf16x8 kf2 = *(const bf16x8*)(kp + 32);
        bf16x8 kf3 = *(const bf16x8*)(kp + 48);

        // V B-fragments: issue now so latency hides under softmax
        const short* vp = Vp + (size_t)l31 * S_ + kv0 + hi * 8;
        bf16x8 vf00 = *(const bf16x8*)(vp);
        bf16x8 vf01 = *(const bf16x8*)(vp + 16);
        bf16x8 vf10 = *(const bf16x8*)(vp + 32 * S_);
        bf16x8 vf11 = *(const bf16x8*)(vp + 32 * S_ + 16);

        f32x16 s;
        #pragma unroll
        for (int r = 0; r < 16; r++) s[r] = 0.f;
        s = __builtin_amdgcn_mfma_f32_32x32x16_bf16(kf0, qf[0], s, 0, 0, 0);
        s = __builtin_amdgcn_mfma_f32_32x32x16_bf16(kf1, qf[1], s, 0, 0, 0);
        s = __builtin_amdgcn_mfma_f32_32x32x16_bf16(kf2, qf[2], s, 0, 0, 0);
        s = __builtin_amdgcn_mfma_f32_32x32x16_bf16(kf3, qf[3], s, 0, 0, 0);

        // in-register max tree over 16, then cross-half combine
        float t0 = fmaxf(s[0], s[1]),   t1 = fmaxf(s[2], s[3]);
        float t2 = fmaxf(s[4], s[5]),   t3 = fmaxf(s[6], s[7]);
        float t4 = fmaxf(s[8], s[9]),   t5 = fmaxf(s[10], s[11]);
        float t6 = fmaxf(s[12], s[13]), t7 = fmaxf(s[14], s[15]);
        float u0 = fmaxf(t0, t1), u1 = fmaxf(t2, t3);
        float u2 = fmaxf(t4, t5), u3 = fmaxf(t6, t7);
        float pmax = fmaxf(fmaxf(u0, u1), fmaxf(u2, u3));
        pmax = fmaxf(pmax, __shfl_xor(pmax, 32));

        // defer-max (T13): rescale only when the running max grew by >8 (log2)
        if (!__all(pmax <= mreg + 8.f)) {
            float mn = fmaxf(mreg, pmax);
            float sc = exp2_fast(mreg - mn);
            mreg = mn; lsum *= sc;
            #pragma unroll
            for (int r = 0; r < 16; r++) { o0[r] *= sc; o1[r] *= sc; }
        }

        #pragma unroll
        for (int r = 0; r < 16; r++) s[r] = exp2_fast(s[r] - mreg);

        float a0 = s[0] + s[1],   a1 = s[2] + s[3];
        float a2 = s[4] + s[5],   a3 = s[6] + s[7];
        float a4 = s[8] + s[9],   a5 = s[10] + s[11];
        float a6 = s[12] + s[13], a7 = s[14] + s[15];
        float b0v = a0 + a1, b1v = a2 + a3, b2v = a4 + a5, b3v = a6 + a7;
        float rsum = (b0v + b1v) + (b2v + b3v);
        rsum += __shfl_xor(rsum, 32);
        lsum += rsum;

        // pack P -> bf16 A-fragments (T12: cvt_pk + cross-half exchange)
        unsigned c0 = cvt_pk_bf16(s[0], s[1]);
        unsigned c1 = cvt_pk_bf16(s[2], s[3]);
        unsigned c2 = cvt_pk_bf16(s[4], s[5]);
        unsigned c3 = cvt_pk_bf16(s[6], s[7]);
        unsigned c4 = cvt_pk_bf16(s[8], s[9]);
        unsigned c5 = cvt_pk_bf16(s[10], s[11]);
        unsigned c6 = cvt_pk_bf16(s[12], s[13]);
        unsigned c7 = cvt_pk_bf16(s[14], s[15]);
        unsigned x0 = (unsigned)__shfl_xor((int)c0, 32);
        unsigned x1 = (unsigned)__shfl_xor((int)c1, 32);
        unsigned x2 = (unsigned)__shfl_xor((int)c2, 32);
        unsigned x3 = (unsigned)__shfl_xor((int)c3, 32);
        unsigned x4 = (unsigned)__shfl_xor((int)c4, 32);
        unsigned x5 = (unsigned)__shfl_xor((int)c5, 32);
        unsigned x6 = (unsigned)__shfl_xor((int)c6, 32);
        unsigned x7 = (unsigned)__shfl_xor((int)c7, 32);

        union U { unsigned u[4]; bf16x8 v; };
        U f0, f1;
        f0.u[0] = hi ? x2 : c0;  f0.u[1] = hi ? x3 : c1;
        f0.u[2] = hi ? c2 : x0;  f0.u[3] = hi ? c3 : x1;
        f1.u[0] = hi ? x6 : c4;  f1.u[1] = hi ? x7 : c5;
        f1.u[2] = hi ? c6 : x4;  f1.u[3] = hi ? c7 : x5;

        o0 = __builtin_amdgcn_mfma_f32_32x32x16_bf16(f0.v, vf00, o0, 0, 0, 0);
        o0 = __builtin_amdgcn_mfma_f32_32x32x16_bf16(f1.v, vf01, o0, 0, 0, 0);
        o1 = __builtin_amdgcn_mfma_f32_32x32x16_bf16(f0.v, vf10, o1, 0, 0, 0);
        o1 = __builtin_amdgcn_mfma_f32_32x32x16_bf16(f1.v, vf11, o1, 0, 0, 0);
    }

    // epilogue: redistribute lsum across the C/D row layout, normalize, store
    if (hi == 0) lsum_lds[w][l31] = lsum;
    __asm__ volatile("" ::: "memory");   // keep write before reads
    #pragma unroll
    for (int r = 0; r < 16; r++) {
        int crow = (r & 3) + ((r >> 2) << 3) + (hi << 2);
        float inv = rcp_fast(lsum_lds[w][crow]);
        float* op = out + ((size_t)(bb * S_ + qbase + crow)) * D_ + hh * DH_ + l31;
        op[0]  = o0[r] * inv;
        op[32] = o1[r] * inv;
    }
}

// ---------------------------------------------------------------------------
// Kernel 3: in-place y = LN(2*out + q) * gamma + beta, one block per row.
// ---------------------------------------------------------------------------
__global__ __launch_bounds__(256) void ln_kernel(
    const float* __restrict__ qin, const float* __restrict__ gamma,
    const float* __restrict__ beta, float* __restrict__ out)
{
    int row = blockIdx.x;
    int tid = threadIdx.x;
    size_t base = (size_t)row * D_;

    float vbuf[3];
    float sum = 0.f, sq = 0.f;
    #pragma unroll
    for (int i = 0; i < 3; i++) {
        int idx = tid + i * 256;
        float x = 2.f * out[base + idx] + qin[base + idx];
        vbuf[i] = x;
        sum += x;
        sq  += x * x;
    }
    #pragma unroll
    for (int msk = 1; msk < 64; msk <<= 1) {
        sum += __shfl_xor(sum, msk);
        sq  += __shfl_xor(sq, msk);
    }
    __shared__ float s1[4], s2[4];
    if ((tid & 63) == 0) { s1[tid >> 6] = sum; s2[tid >> 6] = sq; }
    __syncthreads();
    sum = s1[0] + s1[1] + s1[2] + s1[3];
    sq  = s2[0] + s2[1] + s2[2] + s2[3];
    float mu   = sum * (1.f / D_);
    float var  = sq * (1.f / D_) - mu * mu;
    float rstd = rsqrtf(var + 1e-5f);
    #pragma unroll
    for (int i = 0; i < 3; i++) {
        int idx = tid + i * 256;
        out[base + idx] = (vbuf[i] - mu) * rstd * gamma[idx] + beta[idx];
    }
}

// ---------------------------------------------------------------------------
extern "C" void kernel_launch(void* const* d_in, const int* in_sizes, int n_in,
                              void* d_out, int out_size, void* d_ws, size_t ws_size,
                              hipStream_t stream)
{
    const float* q     = (const float*)d_in[0];
    const float* k     = (const float*)d_in[1];
    const float* v     = (const float*)d_in[2];
    const float* W     = (const float*)d_in[3];
    const float* gamma = (const float*)d_in[4];
    const float* beta  = (const float*)d_in[5];

    size_t per = (size_t)B_ * H_ * S_ * DH_;
    short* q1  = (short*)d_ws;
    short* k1  = q1 + per;
    short* v1t = k1 + per;
    float* out = (float*)d_out;

    proj_kernel<<<dim3(384 * 12), dim3(256), 0, stream>>>(q, k, v, W, q1, k1, v1t);
    attn_kernel<<<dim3(768), dim3(256), 0, stream>>>(q1, k1, v1t, out);
    ln_kernel<<<dim3(B_ * S_), dim3(256), 0, stream>>>(q, gamma, beta, out);
}

// Round 3
// 173.464 us; speedup vs baseline: 1.8945x; 1.2767x over previous
//
#include <hip/hip_runtime.h>
#include <hip/hip_bf16.h>

// Problem constants (B,S,D,H fixed by setup_inputs)
#define B_  8
#define S_  1024
#define D_  768
#define H_  12
#define DH_ 64

typedef __attribute__((ext_vector_type(8))) short bf16x8;
typedef __attribute__((ext_vector_type(4))) float f32x4;
typedef __attribute__((ext_vector_type(16))) float f32x16;

__device__ inline short f2bf(float f) {
    unsigned u = __builtin_bit_cast(unsigned, f);
    u = (u + 0x7fffu + ((u >> 16) & 1u)) >> 16;   // RNE
    return (short)u;
}
__device__ inline float exp2_fast(float x) {
    float r; asm("v_exp_f32 %0, %1" : "=v"(r) : "v"(x)); return r;
}
__device__ inline unsigned cvt_pk_bf16(float lo, float hi) {
    unsigned r; asm("v_cvt_pk_bf16_f32 %0, %1, %2" : "=v"(r) : "v"(lo), "v"(hi)); return r;
}
__device__ inline float rcp_fast(float x) {
    float r; asm("v_rcp_f32 %0, %1" : "=v"(r) : "v"(x)); return r;
}

// ---------------------------------------------------------------------------
// Kernel 1 (v2): Y = relu(X @ W^T), X in {q,k,v} stacked along M (24576 rows).
// 128x128 tile, BK=64, 4 waves in 2x2, each wave 64x64 (4x4 16x16x32 frags).
// Register-staged f32 -> cvt_pk bf16 -> LDS (stride 72 shorts: 16B-aligned,
// <=2-way bank aliasing). Raw-barrier pipeline: next K-step's global loads
// are issued before the barrier and stay in flight under the MFMA phase
// (no vmcnt drain -- only lgkmcnt(0) for ds_write visibility).
// Outputs bf16: q1,k1 as [B][H][S][Dh]; v as [B][H][Dh][S] (transposed).
// k1 pre-scaled by 1/sqrt(Dh)*log2(e) so attention works in exp2 domain.
// Epilogue: LDS transpose -> b128 coalesced stores.
// ---------------------------------------------------------------------------
__global__ __launch_bounds__(256) void proj_kernel(
    const float* __restrict__ q, const float* __restrict__ k,
    const float* __restrict__ v, const float* __restrict__ W,
    short* __restrict__ q1, short* __restrict__ k1, short* __restrict__ v1t)
{
    __shared__ __align__(16) char lds_raw[36864];
    short (*As)[72]  = reinterpret_cast<short(*)[72]>(lds_raw);          // [128][72]
    short (*Bs)[72]  = reinterpret_cast<short(*)[72]>(lds_raw + 18432);  // [128][72]
    short (*Ts)[136] = reinterpret_cast<short(*)[136]>(lds_raw);         // epilogue overlay

    // XCD-chunked swizzle: 1152 blocks = 8 XCDs x 144; within an XCD the 6
    // n-tiles of each m-panel are consecutive -> A-panel reuse in one L2.
    int p  = blockIdx.x;
    int L  = (p & 7) * 144 + (p >> 3);
    int mt = L / 6, nt = L % 6;
    int t  = mt >> 6;                    // 64 m-tiles per input: 0=q,1=k,2=v
    int m0 = (mt & 63) << 7;             // row offset within input [0,8192)
    int n0 = nt << 7;                    // col offset [0,768)
    const float* X = (t == 0) ? q : (t == 1) ? k : v;

    int tid  = threadIdx.x;
    int lane = tid & 63;
    int w    = tid >> 6;
    int wr   = w >> 1, wc = w & 1;
    int l15  = lane & 15;
    int g    = lane >> 4;                // 0..3

    int srow = tid >> 4;                 // staging row-within-round (0..15)
    int scol = (tid & 15) << 2;          // staging f32 col (0..60)

    const float* ax = X + (size_t)(m0 + srow) * D_ + scol;
    const float* bx = W + (size_t)(n0 + srow) * D_ + scol;

    f32x4 acc[4][4];
    #pragma unroll
    for (int m = 0; m < 4; m++)
        #pragma unroll
        for (int n = 0; n < 4; n++) acc[m][n] = (f32x4){0.f, 0.f, 0.f, 0.f};

    // prologue: loads for K-step 0
    f32x4 la[8], lb[8];
    #pragma unroll
    for (int r = 0; r < 8; r++) {
        la[r] = *(const f32x4*)(ax + r * 16 * D_);
        lb[r] = *(const f32x4*)(bx + r * 16 * D_);
    }

    for (int kb = 0; kb < D_; kb += 64) {
        asm volatile("" ::: "memory");
        __builtin_amdgcn_s_barrier();        // A: all waves done reading LDS
        asm volatile("" ::: "memory");
        #pragma unroll
        for (int r = 0; r < 8; r++) {        // convert + write (fused: low VGPR)
            uint2 ua, ub;
            ua.x = cvt_pk_bf16(la[r][0], la[r][1]);
            ua.y = cvt_pk_bf16(la[r][2], la[r][3]);
            ub.x = cvt_pk_bf16(lb[r][0], lb[r][1]);
            ub.y = cvt_pk_bf16(lb[r][2], lb[r][3]);
            *(uint2*)&As[r * 16 + srow][scol] = ua;
            *(uint2*)&Bs[r * 16 + srow][scol] = ub;
        }
        if (kb + 64 < D_) {                  // prefetch next K-step (stays in
            #pragma unroll                   // flight across the barrier)
            for (int r = 0; r < 8; r++) {
                la[r] = *(const f32x4*)(ax + kb + 64 + r * 16 * D_);
                lb[r] = *(const f32x4*)(bx + kb + 64 + r * 16 * D_);
            }
        }
        asm volatile("s_waitcnt lgkmcnt(0)" ::: "memory");  // ds_writes visible
        __builtin_amdgcn_s_barrier();        // B
        __builtin_amdgcn_sched_barrier(0);
        #pragma unroll
        for (int kk = 0; kk < 2; kk++) {
            int c = kk * 32 + (g << 3);
            bf16x8 af[4], bfv[4];
            #pragma unroll
            for (int m = 0; m < 4; m++)
                af[m] = *(const bf16x8*)&As[wr * 64 + m * 16 + l15][c];
            #pragma unroll
            for (int n = 0; n < 4; n++)
                bfv[n] = *(const bf16x8*)&Bs[wc * 64 + n * 16 + l15][c];
            #pragma unroll
            for (int m = 0; m < 4; m++)
                #pragma unroll
                for (int n = 0; n < 4; n++)
                    acc[m][n] = __builtin_amdgcn_mfma_f32_16x16x32_bf16(
                        af[m], bfv[n], acc[m][n], 0, 0, 0);
        }
    }

    // Epilogue: relu(+scale) -> bf16 -> LDS transpose -> b128 stores.
    __syncthreads();                         // all MFMA reads complete
    const float sc1 = (t == 1) ? 0.18033688011112793f : 1.0f;  // 1/8*log2(e)
    #pragma unroll
    for (int m = 0; m < 4; m++) {
        int rb = wr * 64 + m * 16 + (g << 2);
        #pragma unroll
        for (int n = 0; n < 4; n++) {
            int cb = wc * 64 + n * 16 + l15;
            #pragma unroll
            for (int r = 0; r < 4; r++) {
                short vv = f2bf(fmaxf(acc[m][n][r], 0.f) * sc1);
                if (t == 2) Ts[cb][rb + r] = vv;     // v: store transposed
                else        Ts[rb + r][cb] = vv;
            }
        }
    }
    __syncthreads();
    int row = tid >> 1;
    int c0  = (tid & 1) << 6;
    if (t == 2) {
        int gc = n0 + row;                   // global N-col = (h,dh)
        int h = gc >> 6, dh = gc & 63;
        int bb = m0 >> 10, s0 = m0 & 1023;
        short* dst = v1t + (((size_t)bb * H_ + h) * DH_ + dh) * S_ + s0 + c0;
        #pragma unroll
        for (int j = 0; j < 8; j++)
            *(bf16x8*)(dst + j * 8) = *(const bf16x8*)&Ts[row][c0 + j * 8];
    } else {
        int m = m0 + row;
        int bb = m >> 10, ss = m & 1023;
        int h = (n0 >> 6) + (tid & 1);
        short* dst = (t ? k1 : q1) + (((size_t)bb * H_ + h) * S_ + ss) * DH_;
        #pragma unroll
        for (int j = 0; j < 8; j++)
            *(bf16x8*)(dst + j * 8) = *(const bf16x8*)&Ts[row][c0 + j * 8];
    }
}

// ---------------------------------------------------------------------------
// Kernel 2: flash attention, swapped-QK^T 32x32x16 structure (unchanged).
// ---------------------------------------------------------------------------
__global__ __launch_bounds__(256) void attn_kernel(
    const short* __restrict__ q1, const short* __restrict__ k1,
    const short* __restrict__ v1t, float* __restrict__ out)
{
    __shared__ float lsum_lds[4][32];

    int d    = blockIdx.x;                       // 0..767
    int head = (d & 7) + ((d >> 6) << 3);        // 0..95
    int qi   = (d >> 3) & 7;
    int bb   = head / H_, hh = head % H_;

    int tid = threadIdx.x, lane = tid & 63, w = tid >> 6;
    int l31 = lane & 31, hi = lane >> 5;
    int qbase = (qi * 4 + w) * 32;

    const short* Qp = q1  + (size_t)head * S_ * DH_;
    const short* Kp = k1  + (size_t)head * S_ * DH_;
    const short* Vp = v1t + (size_t)head * DH_ * S_;

    bf16x8 qf[4];
    #pragma unroll
    for (int kb = 0; kb < 4; kb++)
        qf[kb] = *(const bf16x8*)(Qp + (size_t)(qbase + l31) * DH_ + kb * 16 + hi * 8);

    f32x16 o0, o1;
    #pragma unroll
    for (int r = 0; r < 16; r++) { o0[r] = 0.f; o1[r] = 0.f; }
    float mreg = -1e30f, lsum = 0.f;

    for (int kv0 = 0; kv0 < S_; kv0 += 32) {
        const short* kp = Kp + (size_t)(kv0 + l31) * DH_ + hi * 8;
        bf16x8 kf0 = *(const bf16x8*)(kp);
        bf16x8 kf1 = *(const bf16x8*)(kp + 16);
        bf16x8 kf2 = *(const bf16x8*)(kp + 32);
        bf16x8 kf3 = *(const bf16x8*)(kp + 48);

        const short* vp = Vp + (size_t)l31 * S_ + kv0 + hi * 8;
        bf16x8 vf00 = *(const bf16x8*)(vp);
        bf16x8 vf01 = *(const bf16x8*)(vp + 16);
        bf16x8 vf10 = *(const bf16x8*)(vp + 32 * S_);
        bf16x8 vf11 = *(const bf16x8*)(vp + 32 * S_ + 16);

        f32x16 s;
        #pragma unroll
        for (int r = 0; r < 16; r++) s[r] = 0.f;
        s = __builtin_amdgcn_mfma_f32_32x32x16_bf16(kf0, qf[0], s, 0, 0, 0);
        s = __builtin_amdgcn_mfma_f32_32x32x16_bf16(kf1, qf[1], s, 0, 0, 0);
        s = __builtin_amdgcn_mfma_f32_32x32x16_bf16(kf2, qf[2], s, 0, 0, 0);
        s = __builtin_amdgcn_mfma_f32_32x32x16_bf16(kf3, qf[3], s, 0, 0, 0);

        float t0 = fmaxf(s[0], s[1]),   t1 = fmaxf(s[2], s[3]);
        float t2 = fmaxf(s[4], s[5]),   t3 = fmaxf(s[6], s[7]);
        float t4 = fmaxf(s[8], s[9]),   t5 = fmaxf(s[10], s[11]);
        float t6 = fmaxf(s[12], s[13]), t7 = fmaxf(s[14], s[15]);
        float u0 = fmaxf(t0, t1), u1 = fmaxf(t2, t3);
        float u2 = fmaxf(t4, t5), u3 = fmaxf(t6, t7);
        float pmax = fmaxf(fmaxf(u0, u1), fmaxf(u2, u3));
        pmax = fmaxf(pmax, __shfl_xor(pmax, 32));

        if (!__all(pmax <= mreg + 8.f)) {
            float mn = fmaxf(mreg, pmax);
            float sc = exp2_fast(mreg - mn);
            mreg = mn; lsum *= sc;
            #pragma unroll
            for (int r = 0; r < 16; r++) { o0[r] *= sc; o1[r] *= sc; }
        }

        #pragma unroll
        for (int r = 0; r < 16; r++) s[r] = exp2_fast(s[r] - mreg);

        float a0 = s[0] + s[1],   a1 = s[2] + s[3];
        float a2 = s[4] + s[5],   a3 = s[6] + s[7];
        float a4 = s[8] + s[9],   a5 = s[10] + s[11];
        float a6 = s[12] + s[13], a7 = s[14] + s[15];
        float b0v = a0 + a1, b1v = a2 + a3, b2v = a4 + a5, b3v = a6 + a7;
        float rsum = (b0v + b1v) + (b2v + b3v);
        rsum += __shfl_xor(rsum, 32);
        lsum += rsum;

        unsigned c0 = cvt_pk_bf16(s[0], s[1]);
        unsigned c1 = cvt_pk_bf16(s[2], s[3]);
        unsigned c2 = cvt_pk_bf16(s[4], s[5]);
        unsigned c3 = cvt_pk_bf16(s[6], s[7]);
        unsigned c4 = cvt_pk_bf16(s[8], s[9]);
        unsigned c5 = cvt_pk_bf16(s[10], s[11]);
        unsigned c6 = cvt_pk_bf16(s[12], s[13]);
        unsigned c7 = cvt_pk_bf16(s[14], s[15]);
        unsigned x0 = (unsigned)__shfl_xor((int)c0, 32);
        unsigned x1 = (unsigned)__shfl_xor((int)c1, 32);
        unsigned x2 = (unsigned)__shfl_xor((int)c2, 32);
        unsigned x3 = (unsigned)__shfl_xor((int)c3, 32);
        unsigned x4 = (unsigned)__shfl_xor((int)c4, 32);
        unsigned x5 = (unsigned)__shfl_xor((int)c5, 32);
        unsigned x6 = (unsigned)__shfl_xor((int)c6, 32);
        unsigned x7 = (unsigned)__shfl_xor((int)c7, 32);

        union U { unsigned u[4]; bf16x8 v; };
        U f0, f1;
        f0.u[0] = hi ? x2 : c0;  f0.u[1] = hi ? x3 : c1;
        f0.u[2] = hi ? c2 : x0;  f0.u[3] = hi ? c3 : x1;
        f1.u[0] = hi ? x6 : c4;  f1.u[1] = hi ? x7 : c5;
        f1.u[2] = hi ? c6 : x4;  f1.u[3] = hi ? c7 : x5;

        o0 = __builtin_amdgcn_mfma_f32_32x32x16_bf16(f0.v, vf00, o0, 0, 0, 0);
        o0 = __builtin_amdgcn_mfma_f32_32x32x16_bf16(f1.v, vf01, o0, 0, 0, 0);
        o1 = __builtin_amdgcn_mfma_f32_32x32x16_bf16(f0.v, vf10, o1, 0, 0, 0);
        o1 = __builtin_amdgcn_mfma_f32_32x32x16_bf16(f1.v, vf11, o1, 0, 0, 0);
    }

    if (hi == 0) lsum_lds[w][l31] = lsum;
    __asm__ volatile("" ::: "memory");
    #pragma unroll
    for (int r = 0; r < 16; r++) {
        int crow = (r & 3) + ((r >> 2) << 3) + (hi << 2);
        float inv = rcp_fast(lsum_lds[w][crow]);
        float* op = out + ((size_t)(bb * S_ + qbase + crow)) * D_ + hh * DH_ + l31;
        op[0]  = o0[r] * inv;
        op[32] = o1[r] * inv;
    }
}

// ---------------------------------------------------------------------------
// Kernel 3: in-place y = LN(2*out + q) * gamma + beta, one block per row.
// ---------------------------------------------------------------------------
__global__ __launch_bounds__(256) void ln_kernel(
    const float* __restrict__ qin, const float* __restrict__ gamma,
    const float* __restrict__ beta, float* __restrict__ out)
{
    int row = blockIdx.x;
    int tid = threadIdx.x;
    size_t base = (size_t)row * D_;

    float vbuf[3];
    float sum = 0.f, sq = 0.f;
    #pragma unroll
    for (int i = 0; i < 3; i++) {
        int idx = tid + i * 256;
        float x = 2.f * out[base + idx] + qin[base + idx];
        vbuf[i] = x;
        sum += x;
        sq  += x * x;
    }
    #pragma unroll
    for (int msk = 1; msk < 64; msk <<= 1) {
        sum += __shfl_xor(sum, msk);
        sq  += __shfl_xor(sq, msk);
    }
    __shared__ float s1[4], s2[4];
    if ((tid & 63) == 0) { s1[tid >> 6] = sum; s2[tid >> 6] = sq; }
    __syncthreads();
    sum = s1[0] + s1[1] + s1[2] + s1[3];
    sq  = s2[0] + s2[1] + s2[2] + s2[3];
    float mu   = sum * (1.f / D_);
    float var  = sq * (1.f / D_) - mu * mu;
    float rstd = rsqrtf(var + 1e-5f);
    #pragma unroll
    for (int i = 0; i < 3; i++) {
        int idx = tid + i * 256;
        out[base + idx] = (vbuf[i] - mu) * rstd * gamma[idx] + beta[idx];
    }
}

// ---------------------------------------------------------------------------
extern "C" void kernel_launch(void* const* d_in, const int* in_sizes, int n_in,
                              void* d_out, int out_size, void* d_ws, size_t ws_size,
                              hipStream_t stream)
{
    const float* q     = (const float*)d_in[0];
    const float* k     = (const float*)d_in[1];
    const float* v     = (const float*)d_in[2];
    const float* W     = (const float*)d_in[3];
    const float* gamma = (const float*)d_in[4];
    const float* beta  = (const float*)d_in[5];

    size_t per = (size_t)B_ * H_ * S_ * DH_;
    short* q1  = (short*)d_ws;
    short* k1  = q1 + per;
    short* v1t = k1 + per;
    float* out = (float*)d_out;

    // 192 m-tiles (3 inputs x 64) x 6 n-tiles = 1152 blocks
    proj_kernel<<<dim3(1152), dim3(256), 0, stream>>>(q, k, v, W, q1, k1, v1t);
    attn_kernel<<<dim3(768), dim3(256), 0, stream>>>(q1, k1, v1t, out);
    ln_kernel<<<dim3(B_ * S_), dim3(256), 0, stream>>>(q, gamma, beta, out);
}

// Round 5
// 173.005 us; speedup vs baseline: 1.8995x; 1.0027x over previous
//
#include <hip/hip_runtime.h>
#include <hip/hip_bf16.h>

// Problem constants (B,S,D,H fixed by setup_inputs)
#define B_  8
#define S_  1024
#define D_  768
#define H_  12
#define DH_ 64

typedef __attribute__((ext_vector_type(8))) short bf16x8;
typedef __attribute__((ext_vector_type(4))) float f32x4;
typedef __attribute__((ext_vector_type(16))) float f32x16;

__device__ inline short f2bf(float f) {
    unsigned u = __builtin_bit_cast(unsigned, f);
    u = (u + 0x7fffu + ((u >> 16) & 1u)) >> 16;   // RNE
    return (short)u;
}
__device__ inline float exp2_fast(float x) {
    float r; asm("v_exp_f32 %0, %1" : "=v"(r) : "v"(x)); return r;
}
__device__ inline unsigned cvt_pk_bf16(float lo, float hi) {
    unsigned r; asm("v_cvt_pk_bf16_f32 %0, %1, %2" : "=v"(r) : "v"(lo), "v"(hi)); return r;
}
__device__ inline float rcp_fast(float x) {
    float r; asm("v_rcp_f32 %0, %1" : "=v"(r) : "v"(x)); return r;
}
// Builtin permlane32_swap (compiler handles the VALU->permlane hazard nops;
// raw inline asm for this instruction produced stale-register reads in R4).
// Returns: r[0] = [a.row0|b.row0], r[1] = [a.row1|b.row1].
__device__ inline void plswap(unsigned& a, unsigned& b) {
    auto r = __builtin_amdgcn_permlane32_swap(a, b, false, false);
    a = r[0]; b = r[1];
}
// For each lane: {x(self-image), x(partner-image)} covering {x[lane],x[lane^32]}
__device__ inline float2 xhalves(float x) {
    unsigned u = __builtin_bit_cast(unsigned, x);
    auto r = __builtin_amdgcn_permlane32_swap(u, u, false, false);
    return make_float2(__builtin_bit_cast(float, r[0]),
                       __builtin_bit_cast(float, r[1]));
}

// ---------------------------------------------------------------------------
// Kernel 1 (v2): Y = relu(X @ W^T), X in {q,k,v} stacked along M (24576 rows).
// 128x128 tile, BK=64, raw-barrier pipeline (unchanged from round 2).
// ---------------------------------------------------------------------------
__global__ __launch_bounds__(256) void proj_kernel(
    const float* __restrict__ q, const float* __restrict__ k,
    const float* __restrict__ v, const float* __restrict__ W,
    short* __restrict__ q1, short* __restrict__ k1, short* __restrict__ v1t)
{
    __shared__ __align__(16) char lds_raw[36864];
    short (*As)[72]  = reinterpret_cast<short(*)[72]>(lds_raw);          // [128][72]
    short (*Bs)[72]  = reinterpret_cast<short(*)[72]>(lds_raw + 18432);  // [128][72]
    short (*Ts)[136] = reinterpret_cast<short(*)[136]>(lds_raw);         // epilogue overlay

    int p  = blockIdx.x;
    int L  = (p & 7) * 144 + (p >> 3);
    int mt = L / 6, nt = L % 6;
    int t  = mt >> 6;                    // 0=q,1=k,2=v
    int m0 = (mt & 63) << 7;
    int n0 = nt << 7;
    const float* X = (t == 0) ? q : (t == 1) ? k : v;

    int tid  = threadIdx.x;
    int lane = tid & 63;
    int w    = tid >> 6;
    int wr   = w >> 1, wc = w & 1;
    int l15  = lane & 15;
    int g    = lane >> 4;

    int srow = tid >> 4;
    int scol = (tid & 15) << 2;

    const float* ax = X + (size_t)(m0 + srow) * D_ + scol;
    const float* bx = W + (size_t)(n0 + srow) * D_ + scol;

    f32x4 acc[4][4];
    #pragma unroll
    for (int m = 0; m < 4; m++)
        #pragma unroll
        for (int n = 0; n < 4; n++) acc[m][n] = (f32x4){0.f, 0.f, 0.f, 0.f};

    f32x4 la[8], lb[8];
    #pragma unroll
    for (int r = 0; r < 8; r++) {
        la[r] = *(const f32x4*)(ax + r * 16 * D_);
        lb[r] = *(const f32x4*)(bx + r * 16 * D_);
    }

    for (int kb = 0; kb < D_; kb += 64) {
        asm volatile("" ::: "memory");
        __builtin_amdgcn_s_barrier();        // A: all waves done reading LDS
        asm volatile("" ::: "memory");
        #pragma unroll
        for (int r = 0; r < 8; r++) {
            uint2 ua, ub;
            ua.x = cvt_pk_bf16(la[r][0], la[r][1]);
            ua.y = cvt_pk_bf16(la[r][2], la[r][3]);
            ub.x = cvt_pk_bf16(lb[r][0], lb[r][1]);
            ub.y = cvt_pk_bf16(lb[r][2], lb[r][3]);
            *(uint2*)&As[r * 16 + srow][scol] = ua;
            *(uint2*)&Bs[r * 16 + srow][scol] = ub;
        }
        if (kb + 64 < D_) {
            #pragma unroll
            for (int r = 0; r < 8; r++) {
                la[r] = *(const f32x4*)(ax + kb + 64 + r * 16 * D_);
                lb[r] = *(const f32x4*)(bx + kb + 64 + r * 16 * D_);
            }
        }
        asm volatile("s_waitcnt lgkmcnt(0)" ::: "memory");
        __builtin_amdgcn_s_barrier();        // B
        __builtin_amdgcn_sched_barrier(0);
        #pragma unroll
        for (int kk = 0; kk < 2; kk++) {
            int c = kk * 32 + (g << 3);
            bf16x8 af[4], bfv[4];
            #pragma unroll
            for (int m = 0; m < 4; m++)
                af[m] = *(const bf16x8*)&As[wr * 64 + m * 16 + l15][c];
            #pragma unroll
            for (int n = 0; n < 4; n++)
                bfv[n] = *(const bf16x8*)&Bs[wc * 64 + n * 16 + l15][c];
            #pragma unroll
            for (int m = 0; m < 4; m++)
                #pragma unroll
                for (int n = 0; n < 4; n++)
                    acc[m][n] = __builtin_amdgcn_mfma_f32_16x16x32_bf16(
                        af[m], bfv[n], acc[m][n], 0, 0, 0);
        }
    }

    __syncthreads();
    const float sc1 = (t == 1) ? 0.18033688011112793f : 1.0f;  // 1/8*log2(e)
    #pragma unroll
    for (int m = 0; m < 4; m++) {
        int rb = wr * 64 + m * 16 + (g << 2);
        #pragma unroll
        for (int n = 0; n < 4; n++) {
            int cb = wc * 64 + n * 16 + l15;
            #pragma unroll
            for (int r = 0; r < 4; r++) {
                short vv = f2bf(fmaxf(acc[m][n][r], 0.f) * sc1);
                if (t == 2) Ts[cb][rb + r] = vv;
                else        Ts[rb + r][cb] = vv;
            }
        }
    }
    __syncthreads();
    int row = tid >> 1;
    int c0  = (tid & 1) << 6;
    if (t == 2) {
        int gc = n0 + row;
        int h = gc >> 6, dh = gc & 63;
        int bb = m0 >> 10, s0 = m0 & 1023;
        short* dst = v1t + (((size_t)bb * H_ + h) * DH_ + dh) * S_ + s0 + c0;
        #pragma unroll
        for (int j = 0; j < 8; j++)
            *(bf16x8*)(dst + j * 8) = *(const bf16x8*)&Ts[row][c0 + j * 8];
    } else {
        int m = m0 + row;
        int bb = m >> 10, ss = m & 1023;
        int h = (n0 >> 6) + (tid & 1);
        short* dst = (t ? k1 : q1) + (((size_t)bb * H_ + h) * S_ + ss) * DH_;
        #pragma unroll
        for (int j = 0; j < 8; j++)
            *(bf16x8*)(dst + j * 8) = *(const bf16x8*)&Ts[row][c0 + j * 8];
    }
}

// ---------------------------------------------------------------------------
// Kernel 2 (v4): flash attention, swapped-QK^T 32x32x16.
// - builtin permlane32_swap (hazard-safe) for all cross-half exchanges
// - rescale fix: sc redistributed l31->crow via per-wave LDS on (rare,
//   wave-uniform) rescale events -- o rows are crow-indexed, not l31-indexed
// - ping-pong K/V register prefetch + setprio around MFMA clusters
// ---------------------------------------------------------------------------
__global__ __launch_bounds__(256, 3) void attn_kernel(
    const short* __restrict__ q1, const short* __restrict__ k1,
    const short* __restrict__ v1t, float* __restrict__ out)
{
    __shared__ float lsum_lds[4][32];

    int d    = blockIdx.x;                       // 0..767
    int head = (d & 7) + ((d >> 6) << 3);        // 0..95
    int qi   = (d >> 3) & 7;
    int bb   = head / H_, hh = head % H_;

    int tid = threadIdx.x, lane = tid & 63, w = tid >> 6;
    int l31 = lane & 31, hi = lane >> 5;
    int qbase = (qi * 4 + w) * 32;

    const short* Qp = q1  + (size_t)head * S_ * DH_;
    const short* Kp = k1  + (size_t)head * S_ * DH_;
    const short* Vp = v1t + (size_t)head * DH_ * S_;

    bf16x8 qf[4];
    #pragma unroll
    for (int kb = 0; kb < 4; kb++)
        qf[kb] = *(const bf16x8*)(Qp + (size_t)(qbase + l31) * DH_ + kb * 16 + hi * 8);

    f32x16 o0, o1;
    #pragma unroll
    for (int r = 0; r < 16; r++) { o0[r] = 0.f; o1[r] = 0.f; }
    float mreg = -1e30f, lsum = 0.f;

#define LOADK(P, off) do { \
        const short* _kp = Kp + (size_t)((off) + l31) * DH_ + hi * 8; \
        P##0 = *(const bf16x8*)_kp;        P##1 = *(const bf16x8*)(_kp + 16); \
        P##2 = *(const bf16x8*)(_kp + 32); P##3 = *(const bf16x8*)(_kp + 48); \
    } while (0)
#define LOADV(P, off) do { \
        const short* _vp = Vp + (size_t)l31 * S_ + (off) + hi * 8; \
        P##00 = *(const bf16x8*)_vp;               P##01 = *(const bf16x8*)(_vp + 16); \
        P##10 = *(const bf16x8*)(_vp + 32 * S_);   P##11 = *(const bf16x8*)(_vp + 32 * S_ + 16); \
    } while (0)

    auto tile = [&](bf16x8 k0, bf16x8 k1v, bf16x8 k2, bf16x8 k3,
                    bf16x8 v00, bf16x8 v01, bf16x8 v10, bf16x8 v11) {
        f32x16 s;
        #pragma unroll
        for (int r = 0; r < 16; r++) s[r] = 0.f;
        __builtin_amdgcn_s_setprio(1);
        s = __builtin_amdgcn_mfma_f32_32x32x16_bf16(k0,  qf[0], s, 0, 0, 0);
        s = __builtin_amdgcn_mfma_f32_32x32x16_bf16(k1v, qf[1], s, 0, 0, 0);
        s = __builtin_amdgcn_mfma_f32_32x32x16_bf16(k2,  qf[2], s, 0, 0, 0);
        s = __builtin_amdgcn_mfma_f32_32x32x16_bf16(k3,  qf[3], s, 0, 0, 0);
        __builtin_amdgcn_s_setprio(0);

        float t0 = fmaxf(s[0], s[1]),   t1 = fmaxf(s[2], s[3]);
        float t2 = fmaxf(s[4], s[5]),   t3 = fmaxf(s[6], s[7]);
        float t4 = fmaxf(s[8], s[9]),   t5 = fmaxf(s[10], s[11]);
        float t6 = fmaxf(s[12], s[13]), t7 = fmaxf(s[14], s[15]);
        float u0 = fmaxf(t0, t1), u1 = fmaxf(t2, t3);
        float u2 = fmaxf(t4, t5), u3 = fmaxf(t6, t7);
        float pmax = fmaxf(fmaxf(u0, u1), fmaxf(u2, u3));
        float2 ph = xhalves(pmax);
        pmax = fmaxf(ph.x, ph.y);        // per q-row (l31), equal across halves

        if (!__all(pmax <= mreg + 8.f)) {       // defer-max (T13), log2 domain
            float mn = fmaxf(mreg, pmax);
            float sc = exp2_fast(mreg - mn);
            mreg = mn; lsum *= sc;
            // o0/o1 rows are crow-indexed; sc is l31-indexed. Redistribute
            // through per-wave LDS (rare branch; wave-uniform trigger).
            if (hi == 0) lsum_lds[w][l31] = sc;
            asm volatile("" ::: "memory");
            #pragma unroll
            for (int r = 0; r < 16; r++) {
                int crow = (r & 3) + ((r >> 2) << 3) + (hi << 2);
                float sr = lsum_lds[w][crow];
                o0[r] *= sr; o1[r] *= sr;
            }
        }

        #pragma unroll
        for (int r = 0; r < 16; r++) s[r] = exp2_fast(s[r] - mreg);

        float a0 = s[0] + s[1],   a1 = s[2] + s[3];
        float a2 = s[4] + s[5],   a3 = s[6] + s[7];
        float a4 = s[8] + s[9],   a5 = s[10] + s[11];
        float a6 = s[12] + s[13], a7 = s[14] + s[15];
        float rsum = ((a0 + a1) + (a2 + a3)) + ((a4 + a5) + (a6 + a7));
        float2 rh = xhalves(rsum);
        lsum += rh.x + rh.y;

        // pack P -> bf16 A-fragments: 8 cvt_pk + 4 permlane32_swap, no selects
        unsigned c0 = cvt_pk_bf16(s[0], s[1]);
        unsigned c1 = cvt_pk_bf16(s[2], s[3]);
        unsigned c2 = cvt_pk_bf16(s[4], s[5]);
        unsigned c3 = cvt_pk_bf16(s[6], s[7]);
        unsigned c4 = cvt_pk_bf16(s[8], s[9]);
        unsigned c5 = cvt_pk_bf16(s[10], s[11]);
        unsigned c6 = cvt_pk_bf16(s[12], s[13]);
        unsigned c7 = cvt_pk_bf16(s[14], s[15]);
        plswap(c0, c2);   // c0 -> f0.u[0], c2 -> f0.u[2]
        plswap(c1, c3);
        plswap(c4, c6);
        plswap(c5, c7);

        union U { unsigned u[4]; bf16x8 v; };
        U f0, f1;
        f0.u[0] = c0; f0.u[1] = c1; f0.u[2] = c2; f0.u[3] = c3;
        f1.u[0] = c4; f1.u[1] = c5; f1.u[2] = c6; f1.u[3] = c7;

        __builtin_amdgcn_s_setprio(1);
        o0 = __builtin_amdgcn_mfma_f32_32x32x16_bf16(f0.v, v00, o0, 0, 0, 0);
        o0 = __builtin_amdgcn_mfma_f32_32x32x16_bf16(f1.v, v01, o0, 0, 0, 0);
        o1 = __builtin_amdgcn_mfma_f32_32x32x16_bf16(f0.v, v10, o1, 0, 0, 0);
        o1 = __builtin_amdgcn_mfma_f32_32x32x16_bf16(f1.v, v11, o1, 0, 0, 0);
        __builtin_amdgcn_s_setprio(0);
    };

    bf16x8 ka0, ka1, ka2, ka3, va00, va01, va10, va11;
    bf16x8 kb0, kb1, kb2, kb3, vb00, vb01, vb10, vb11;
    LOADK(ka, 0); LOADV(va, 0);

    for (int kv0 = 0; kv0 < S_; kv0 += 64) {
        LOADK(kb, kv0 + 32); LOADV(vb, kv0 + 32);     // prefetch next half
        tile(ka0, ka1, ka2, ka3, va00, va01, va10, va11);
        if (kv0 + 64 < S_) { LOADK(ka, kv0 + 64); LOADV(va, kv0 + 64); }
        tile(kb0, kb1, kb2, kb3, vb00, vb01, vb10, vb11);
    }
#undef LOADK
#undef LOADV

    if (hi == 0) lsum_lds[w][l31] = lsum;
    __asm__ volatile("" ::: "memory");
    #pragma unroll
    for (int r = 0; r < 16; r++) {
        int crow = (r & 3) + ((r >> 2) << 3) + (hi << 2);
        float inv = rcp_fast(lsum_lds[w][crow]);
        float* op = out + ((size_t)(bb * S_ + qbase + crow)) * D_ + hh * DH_ + l31;
        op[0]  = o0[r] * inv;
        op[32] = o1[r] * inv;
    }
}

// ---------------------------------------------------------------------------
// Kernel 3: in-place y = LN(2*out + q) * gamma + beta, one block per row.
// ---------------------------------------------------------------------------
__global__ __launch_bounds__(256) void ln_kernel(
    const float* __restrict__ qin, const float* __restrict__ gamma,
    const float* __restrict__ beta, float* __restrict__ out)
{
    int row = blockIdx.x;
    int tid = threadIdx.x;
    size_t base = (size_t)row * D_;

    float vbuf[3];
    float sum = 0.f, sq = 0.f;
    #pragma unroll
    for (int i = 0; i < 3; i++) {
        int idx = tid + i * 256;
        float x = 2.f * out[base + idx] + qin[base + idx];
        vbuf[i] = x;
        sum += x;
        sq  += x * x;
    }
    #pragma unroll
    for (int msk = 1; msk < 64; msk <<= 1) {
        sum += __shfl_xor(sum, msk);
        sq  += __shfl_xor(sq, msk);
    }
    __shared__ float s1[4], s2[4];
    if ((tid & 63) == 0) { s1[tid >> 6] = sum; s2[tid >> 6] = sq; }
    __syncthreads();
    sum = s1[0] + s1[1] + s1[2] + s1[3];
    sq  = s2[0] + s2[1] + s2[2] + s2[3];
    float mu   = sum * (1.f / D_);
    float var  = sq * (1.f / D_) - mu * mu;
    float rstd = rsqrtf(var + 1e-5f);
    #pragma unroll
    for (int i = 0; i < 3; i++) {
        int idx = tid + i * 256;
        out[base + idx] = (vbuf[i] - mu) * rstd * gamma[idx] + beta[idx];
    }
}

// ---------------------------------------------------------------------------
extern "C" void kernel_launch(void* const* d_in, const int* in_sizes, int n_in,
                              void* d_out, int out_size, void* d_ws, size_t ws_size,
                              hipStream_t stream)
{
    const float* q     = (const float*)d_in[0];
    const float* k     = (const float*)d_in[1];
    const float* v     = (const float*)d_in[2];
    const float* W     = (const float*)d_in[3];
    const float* gamma = (const float*)d_in[4];
    const float* beta  = (const float*)d_in[5];

    size_t per = (size_t)B_ * H_ * S_ * DH_;
    short* q1  = (short*)d_ws;
    short* k1  = q1 + per;
    short* v1t = k1 + per;
    float* out = (float*)d_out;

    proj_kernel<<<dim3(1152), dim3(256), 0, stream>>>(q, k, v, W, q1, k1, v1t);
    attn_kernel<<<dim3(768), dim3(256), 0, stream>>>(q1, k1, v1t, out);
    ln_kernel<<<dim3(B_ * S_), dim3(256), 0, stream>>>(q, gamma, beta, out);
}

// Round 6
// 120.650 us; speedup vs baseline: 2.7238x; 1.4339x over previous
//
#include <hip/hip_runtime.h>
#include <hip/hip_bf16.h>

// Problem constants (B,S,D,H fixed by setup_inputs)
#define B_  8
#define S_  1024
#define D_  768
#define H_  12
#define DH_ 64

typedef __attribute__((ext_vector_type(8))) short bf16x8;
typedef __attribute__((ext_vector_type(4))) float f32x4;
typedef __attribute__((ext_vector_type(16))) float f32x16;

__device__ inline short f2bf(float f) {
    unsigned u = __builtin_bit_cast(unsigned, f);
    u = (u + 0x7fffu + ((u >> 16) & 1u)) >> 16;   // RNE
    return (short)u;
}
__device__ inline float exp2_fast(float x) {
    float r; asm("v_exp_f32 %0, %1" : "=v"(r) : "v"(x)); return r;
}
__device__ inline unsigned cvt_pk_bf16(float lo, float hi) {
    unsigned r; asm("v_cvt_pk_bf16_f32 %0, %1, %2" : "=v"(r) : "v"(lo), "v"(hi)); return r;
}
__device__ inline float rcp_fast(float x) {
    float r; asm("v_rcp_f32 %0, %1" : "=v"(r) : "v"(x)); return r;
}
// Builtin permlane32_swap (compiler inserts the VALU->permlane hazard waits).
__device__ inline void plswap(unsigned& a, unsigned& b) {
    auto r = __builtin_amdgcn_permlane32_swap(a, b, false, false);
    a = r[0]; b = r[1];
}
__device__ inline float2 xhalves(float x) {
    unsigned u = __builtin_bit_cast(unsigned, x);
    auto r = __builtin_amdgcn_permlane32_swap(u, u, false, false);
    return make_float2(__builtin_bit_cast(float, r[0]),
                       __builtin_bit_cast(float, r[1]));
}

// ---------------------------------------------------------------------------
// Kernel 1 (v2): Y = relu(X @ W^T), unchanged from round 3 (passing).
// ---------------------------------------------------------------------------
__global__ __launch_bounds__(256) void proj_kernel(
    const float* __restrict__ q, const float* __restrict__ k,
    const float* __restrict__ v, const float* __restrict__ W,
    short* __restrict__ q1, short* __restrict__ k1, short* __restrict__ v1t)
{
    __shared__ __align__(16) char lds_raw[36864];
    short (*As)[72]  = reinterpret_cast<short(*)[72]>(lds_raw);          // [128][72]
    short (*Bs)[72]  = reinterpret_cast<short(*)[72]>(lds_raw + 18432);  // [128][72]
    short (*Ts)[136] = reinterpret_cast<short(*)[136]>(lds_raw);         // epilogue overlay

    int p  = blockIdx.x;
    int L  = (p & 7) * 144 + (p >> 3);
    int mt = L / 6, nt = L % 6;
    int t  = mt >> 6;                    // 0=q,1=k,2=v
    int m0 = (mt & 63) << 7;
    int n0 = nt << 7;
    const float* X = (t == 0) ? q : (t == 1) ? k : v;

    int tid  = threadIdx.x;
    int lane = tid & 63;
    int w    = tid >> 6;
    int wr   = w >> 1, wc = w & 1;
    int l15  = lane & 15;
    int g    = lane >> 4;

    int srow = tid >> 4;
    int scol = (tid & 15) << 2;

    const float* ax = X + (size_t)(m0 + srow) * D_ + scol;
    const float* bx = W + (size_t)(n0 + srow) * D_ + scol;

    f32x4 acc[4][4];
    #pragma unroll
    for (int m = 0; m < 4; m++)
        #pragma unroll
        for (int n = 0; n < 4; n++) acc[m][n] = (f32x4){0.f, 0.f, 0.f, 0.f};

    f32x4 la[8], lb[8];
    #pragma unroll
    for (int r = 0; r < 8; r++) {
        la[r] = *(const f32x4*)(ax + r * 16 * D_);
        lb[r] = *(const f32x4*)(bx + r * 16 * D_);
    }

    for (int kb = 0; kb < D_; kb += 64) {
        asm volatile("" ::: "memory");
        __builtin_amdgcn_s_barrier();        // A: all waves done reading LDS
        asm volatile("" ::: "memory");
        #pragma unroll
        for (int r = 0; r < 8; r++) {
            uint2 ua, ub;
            ua.x = cvt_pk_bf16(la[r][0], la[r][1]);
            ua.y = cvt_pk_bf16(la[r][2], la[r][3]);
            ub.x = cvt_pk_bf16(lb[r][0], lb[r][1]);
            ub.y = cvt_pk_bf16(lb[r][2], lb[r][3]);
            *(uint2*)&As[r * 16 + srow][scol] = ua;
            *(uint2*)&Bs[r * 16 + srow][scol] = ub;
        }
        if (kb + 64 < D_) {
            #pragma unroll
            for (int r = 0; r < 8; r++) {
                la[r] = *(const f32x4*)(ax + kb + 64 + r * 16 * D_);
                lb[r] = *(const f32x4*)(bx + kb + 64 + r * 16 * D_);
            }
        }
        asm volatile("s_waitcnt lgkmcnt(0)" ::: "memory");
        __builtin_amdgcn_s_barrier();        // B
        __builtin_amdgcn_sched_barrier(0);
        #pragma unroll
        for (int kk = 0; kk < 2; kk++) {
            int c = kk * 32 + (g << 3);
            bf16x8 af[4], bfv[4];
            #pragma unroll
            for (int m = 0; m < 4; m++)
                af[m] = *(const bf16x8*)&As[wr * 64 + m * 16 + l15][c];
            #pragma unroll
            for (int n = 0; n < 4; n++)
                bfv[n] = *(const bf16x8*)&Bs[wc * 64 + n * 16 + l15][c];
            #pragma unroll
            for (int m = 0; m < 4; m++)
                #pragma unroll
                for (int n = 0; n < 4; n++)
                    acc[m][n] = __builtin_amdgcn_mfma_f32_16x16x32_bf16(
                        af[m], bfv[n], acc[m][n], 0, 0, 0);
        }
    }

    __syncthreads();
    const float sc1 = (t == 1) ? 0.18033688011112793f : 1.0f;  // 1/8*log2(e)
    #pragma unroll
    for (int m = 0; m < 4; m++) {
        int rb = wr * 64 + m * 16 + (g << 2);
        #pragma unroll
        for (int n = 0; n < 4; n++) {
            int cb = wc * 64 + n * 16 + l15;
            #pragma unroll
            for (int r = 0; r < 4; r++) {
                short vv = f2bf(fmaxf(acc[m][n][r], 0.f) * sc1);
                if (t == 2) Ts[cb][rb + r] = vv;
                else        Ts[rb + r][cb] = vv;
            }
        }
    }
    __syncthreads();
    int row = tid >> 1;
    int c0  = (tid & 1) << 6;
    if (t == 2) {
        int gc = n0 + row;
        int h = gc >> 6, dh = gc & 63;
        int bb = m0 >> 10, s0 = m0 & 1023;
        short* dst = v1t + (((size_t)bb * H_ + h) * DH_ + dh) * S_ + s0 + c0;
        #pragma unroll
        for (int j = 0; j < 8; j++)
            *(bf16x8*)(dst + j * 8) = *(const bf16x8*)&Ts[row][c0 + j * 8];
    } else {
        int m = m0 + row;
        int bb = m >> 10, ss = m & 1023;
        int h = (n0 >> 6) + (tid & 1);
        short* dst = (t ? k1 : q1) + (((size_t)bb * H_ + h) * S_ + ss) * DH_;
        #pragma unroll
        for (int j = 0; j < 8; j++)
            *(bf16x8*)(dst + j * 8) = *(const bf16x8*)&Ts[row][c0 + j * 8];
    }
}

// ---------------------------------------------------------------------------
// Kernel 2 (v5): flash attention, swapped-QK^T 32x32x16, block-cooperative
// LDS-staged K/V (T14 async-split, double-buffered, XOR-swizzled).
// - K/V tile (KVBLK=64) staged once per block (4 waves share) instead of
//   per-wave global loads: 4x fewer requests, LDS-latency reads.
// - Pipeline: iter t writes tile t+1 (regs->LDS), issues global loads for
//   tile t+2, computes tile t. One raw s_barrier + lgkmcnt(0) per tile;
//   vmcnt never drained -> ~2K cycles of cover per load (> HBM latency).
// - Swizzle: 16B-slot ^= (row&7) on both write and read (4-way residual
//   conflict = floor for b128 32-lane column reads).
// ---------------------------------------------------------------------------
__global__ __launch_bounds__(256, 3) void attn_kernel(
    const short* __restrict__ q1, const short* __restrict__ k1,
    const short* __restrict__ v1t, float* __restrict__ out)
{
    __shared__ short Klds[2][4096];   // [buf][64 kv rows][64 dh], swizzled
    __shared__ short Vlds[2][4096];   // [buf][64 dh rows][64 kv], swizzled
    __shared__ float lsum_lds[4][32];

    int d    = blockIdx.x;                       // 0..767
    int head = (d & 7) + ((d >> 6) << 3);        // same head -> same XCD
    int qi   = (d >> 3) & 7;
    int bb   = head / H_, hh = head % H_;

    int tid = threadIdx.x, lane = tid & 63, w = tid >> 6;
    int l31 = lane & 31, hi = lane >> 5;
    int qbase = (qi * 4 + w) * 32;

    const short* Qp = q1  + (size_t)head * S_ * DH_;
    const short* Kp = k1  + (size_t)head * S_ * DH_;
    const short* Vp = v1t + (size_t)head * DH_ * S_;

    // staging geometry: thread -> (row r, 16B slot c / c+4)
    int sr = tid >> 2, sc = tid & 3;
    int swz0 = sr * 128 + ((sc       ^ (sr & 7)) << 4);
    int swz1 = sr * 128 + (((sc + 4) ^ (sr & 7)) << 4);

    bf16x8 stK0, stK1, stV0, stV1;

#define LOADST(kvb) do { \
        const short* _kg = Kp + (size_t)((kvb) + sr) * DH_; \
        const short* _vg = Vp + (size_t)sr * S_ + (kvb); \
        stK0 = *(const bf16x8*)(_kg + sc * 8); \
        stK1 = *(const bf16x8*)(_kg + (sc + 4) * 8); \
        stV0 = *(const bf16x8*)(_vg + sc * 8); \
        stV1 = *(const bf16x8*)(_vg + (sc + 4) * 8); \
    } while (0)
#define WRITEST(buf) do { \
        char* _kb = (char*)&Klds[buf][0]; \
        char* _vb = (char*)&Vlds[buf][0]; \
        *(bf16x8*)(_kb + swz0) = stK0; \
        *(bf16x8*)(_kb + swz1) = stK1; \
        *(bf16x8*)(_vb + swz0) = stV0; \
        *(bf16x8*)(_vb + swz1) = stV1; \
    } while (0)

    // Q B-fragments, resident for the whole kernel
    bf16x8 qf[4];
    #pragma unroll
    for (int kb = 0; kb < 4; kb++)
        qf[kb] = *(const bf16x8*)(Qp + (size_t)(qbase + l31) * DH_ + kb * 16 + hi * 8);

    f32x16 o0, o1;
    #pragma unroll
    for (int r = 0; r < 16; r++) { o0[r] = 0.f; o1[r] = 0.f; }
    float mreg = -1e30f, lsum = 0.f;

    int xk = l31 & 7;   // row-XOR for fragment reads (rows = l31 mod 8)

    auto subtile = [&](int cur, int j) {
        const char* Kt = (const char*)&Klds[cur][0];
        const char* Vt = (const char*)&Vlds[cur][0];
        int rK = (32 * j + l31) * 128;
        bf16x8 kf0 = *(const bf16x8*)(Kt + rK + (((0 + hi) ^ xk) << 4));
        bf16x8 kf1 = *(const bf16x8*)(Kt + rK + (((2 + hi) ^ xk) << 4));
        bf16x8 kf2 = *(const bf16x8*)(Kt + rK + (((4 + hi) ^ xk) << 4));
        bf16x8 kf3 = *(const bf16x8*)(Kt + rK + (((6 + hi) ^ xk) << 4));
        int rV0 = l31 * 128, rV1 = (32 + l31) * 128;
        int s0 = ((4 * j + hi) ^ xk) << 4, s1 = ((4 * j + 2 + hi) ^ xk) << 4;
        bf16x8 vf00 = *(const bf16x8*)(Vt + rV0 + s0);
        bf16x8 vf01 = *(const bf16x8*)(Vt + rV0 + s1);
        bf16x8 vf10 = *(const bf16x8*)(Vt + rV1 + s0);
        bf16x8 vf11 = *(const bf16x8*)(Vt + rV1 + s1);

        f32x16 s;
        #pragma unroll
        for (int r = 0; r < 16; r++) s[r] = 0.f;
        __builtin_amdgcn_s_setprio(1);
        s = __builtin_amdgcn_mfma_f32_32x32x16_bf16(kf0, qf[0], s, 0, 0, 0);
        s = __builtin_amdgcn_mfma_f32_32x32x16_bf16(kf1, qf[1], s, 0, 0, 0);
        s = __builtin_amdgcn_mfma_f32_32x32x16_bf16(kf2, qf[2], s, 0, 0, 0);
        s = __builtin_amdgcn_mfma_f32_32x32x16_bf16(kf3, qf[3], s, 0, 0, 0);
        __builtin_amdgcn_s_setprio(0);

        float t0 = fmaxf(s[0], s[1]),   t1 = fmaxf(s[2], s[3]);
        float t2 = fmaxf(s[4], s[5]),   t3 = fmaxf(s[6], s[7]);
        float t4 = fmaxf(s[8], s[9]),   t5 = fmaxf(s[10], s[11]);
        float t6 = fmaxf(s[12], s[13]), t7 = fmaxf(s[14], s[15]);
        float u0 = fmaxf(t0, t1), u1 = fmaxf(t2, t3);
        float u2 = fmaxf(t4, t5), u3 = fmaxf(t6, t7);
        float pmax = fmaxf(fmaxf(u0, u1), fmaxf(u2, u3));
        float2 ph = xhalves(pmax);
        pmax = fmaxf(ph.x, ph.y);

        if (!__all(pmax <= mreg + 8.f)) {       // defer-max (T13), log2 domain
            float mn = fmaxf(mreg, pmax);
            float sc_ = exp2_fast(mreg - mn);
            mreg = mn; lsum *= sc_;
            if (hi == 0) lsum_lds[w][l31] = sc_;
            asm volatile("s_waitcnt lgkmcnt(0)" ::: "memory");
            #pragma unroll
            for (int r = 0; r < 16; r++) {
                int crow = (r & 3) + ((r >> 2) << 3) + (hi << 2);
                float srw = lsum_lds[w][crow];
                o0[r] *= srw; o1[r] *= srw;
            }
        }

        #pragma unroll
        for (int r = 0; r < 16; r++) s[r] = exp2_fast(s[r] - mreg);

        float a0 = s[0] + s[1],   a1 = s[2] + s[3];
        float a2 = s[4] + s[5],   a3 = s[6] + s[7];
        float a4 = s[8] + s[9],   a5 = s[10] + s[11];
        float a6 = s[12] + s[13], a7 = s[14] + s[15];
        float rsum = ((a0 + a1) + (a2 + a3)) + ((a4 + a5) + (a6 + a7));
        float2 rh = xhalves(rsum);
        lsum += rh.x + rh.y;

        unsigned c0 = cvt_pk_bf16(s[0], s[1]);
        unsigned c1 = cvt_pk_bf16(s[2], s[3]);
        unsigned c2 = cvt_pk_bf16(s[4], s[5]);
        unsigned c3 = cvt_pk_bf16(s[6], s[7]);
        unsigned c4 = cvt_pk_bf16(s[8], s[9]);
        unsigned c5 = cvt_pk_bf16(s[10], s[11]);
        unsigned c6 = cvt_pk_bf16(s[12], s[13]);
        unsigned c7 = cvt_pk_bf16(s[14], s[15]);
        plswap(c0, c2);
        plswap(c1, c3);
        plswap(c4, c6);
        plswap(c5, c7);

        union U { unsigned u[4]; bf16x8 v; };
        U f0, f1;
        f0.u[0] = c0; f0.u[1] = c1; f0.u[2] = c2; f0.u[3] = c3;
        f1.u[0] = c4; f1.u[1] = c5; f1.u[2] = c6; f1.u[3] = c7;

        __builtin_amdgcn_s_setprio(1);
        o0 = __builtin_amdgcn_mfma_f32_32x32x16_bf16(f0.v, vf00, o0, 0, 0, 0);
        o0 = __builtin_amdgcn_mfma_f32_32x32x16_bf16(f1.v, vf01, o0, 0, 0, 0);
        o1 = __builtin_amdgcn_mfma_f32_32x32x16_bf16(f0.v, vf10, o1, 0, 0, 0);
        o1 = __builtin_amdgcn_mfma_f32_32x32x16_bf16(f1.v, vf11, o1, 0, 0, 0);
        __builtin_amdgcn_s_setprio(0);
    };

    // ---- pipeline prologue: tile0 -> LDS buf0; tile1 loads in flight ----
    LOADST(0);
    WRITEST(0);                     // auto vmcnt-wait on stK/stV first use
    LOADST(64);
    asm volatile("s_waitcnt lgkmcnt(0)" ::: "memory");
    __builtin_amdgcn_s_barrier();
    asm volatile("" ::: "memory");

    int cur = 0;
    for (int t = 0; t < 16; t++) {
        if (t < 15) {
            WRITEST(cur ^ 1);              // tile t+1 into other buffer
            if (t < 14) LOADST((t + 2) * 64);   // issue tile t+2 loads
        }
        subtile(cur, 0);
        subtile(cur, 1);
        if (t < 15) {
            asm volatile("" ::: "memory");
            asm volatile("s_waitcnt lgkmcnt(0)" ::: "memory");
            __builtin_amdgcn_s_barrier();   // writes visible; reads done
            asm volatile("" ::: "memory");
        }
        cur ^= 1;
    }
#undef LOADST
#undef WRITEST

    if (hi == 0) lsum_lds[w][l31] = lsum;
    asm volatile("s_waitcnt lgkmcnt(0)" ::: "memory");
    #pragma unroll
    for (int r = 0; r < 16; r++) {
        int crow = (r & 3) + ((r >> 2) << 3) + (hi << 2);
        float inv = rcp_fast(lsum_lds[w][crow]);
        float* op = out + ((size_t)(bb * S_ + qbase + crow)) * D_ + hh * DH_ + l31;
        op[0]  = o0[r] * inv;
        op[32] = o1[r] * inv;
    }
}

// ---------------------------------------------------------------------------
// Kernel 3 (v2): y = LN(2*out + q) * gamma + beta; 192 thr/row, f32x4 loads.
// ---------------------------------------------------------------------------
__global__ __launch_bounds__(192) void ln_kernel(
    const float* __restrict__ qin, const float* __restrict__ gamma,
    const float* __restrict__ beta, float* __restrict__ out)
{
    int row = blockIdx.x;
    int tid = threadIdx.x;
    size_t base = (size_t)row * D_ + tid * 4;

    f32x4 o  = *(const f32x4*)(out + base);
    f32x4 qv = *(const f32x4*)(qin + base);
    f32x4 x;
    float sum = 0.f, sq = 0.f;
    #pragma unroll
    for (int i = 0; i < 4; i++) {
        x[i] = 2.f * o[i] + qv[i];
        sum += x[i];
        sq  += x[i] * x[i];
    }
    #pragma unroll
    for (int msk = 1; msk < 64; msk <<= 1) {
        sum += __shfl_xor(sum, msk);
        sq  += __shfl_xor(sq, msk);
    }
    __shared__ float s1[3], s2[3];
    if ((tid & 63) == 0) { s1[tid >> 6] = sum; s2[tid >> 6] = sq; }
    __syncthreads();
    sum = s1[0] + s1[1] + s1[2];
    sq  = s2[0] + s2[1] + s2[2];
    float mu   = sum * (1.f / D_);
    float var  = sq * (1.f / D_) - mu * mu;
    float rstd = rsqrtf(var + 1e-5f);
    f32x4 g = *(const f32x4*)(gamma + tid * 4);
    f32x4 b = *(const f32x4*)(beta + tid * 4);
    f32x4 y;
    #pragma unroll
    for (int i = 0; i < 4; i++)
        y[i] = (x[i] - mu) * rstd * g[i] + b[i];
    *(f32x4*)(out + base) = y;
}

// ---------------------------------------------------------------------------
extern "C" void kernel_launch(void* const* d_in, const int* in_sizes, int n_in,
                              void* d_out, int out_size, void* d_ws, size_t ws_size,
                              hipStream_t stream)
{
    const float* q     = (const float*)d_in[0];
    const float* k     = (const float*)d_in[1];
    const float* v     = (const float*)d_in[2];
    const float* W     = (const float*)d_in[3];
    const float* gamma = (const float*)d_in[4];
    const float* beta  = (const float*)d_in[5];

    size_t per = (size_t)B_ * H_ * S_ * DH_;
    short* q1  = (short*)d_ws;
    short* k1  = q1 + per;
    short* v1t = k1 + per;
    float* out = (float*)d_out;

    proj_kernel<<<dim3(1152), dim3(256), 0, stream>>>(q, k, v, W, q1, k1, v1t);
    attn_kernel<<<dim3(768), dim3(256), 0, stream>>>(q1, k1, v1t, out);
    ln_kernel<<<dim3(B_ * S_), dim3(192), 0, stream>>>(q, gamma, beta, out);
}